// Round 1
// baseline (544.856 us; speedup 1.0000x reference)
//
#include <hip/hip_runtime.h>
#include <math.h>

#define NTOK 3136   // 56*56
#define NKV  784    // 28*28
#define CD   256
#define NH   8
#define HD   32
#define PEW  111    // 2*56-1
#define SCALE 0.17677669529663687f  // 32^-0.5

static __device__ __forceinline__ float4 ld4(const float* p){ return *(const float4*)p; }

// ---- kernel 0: transpose sr_w (OIHW 256,256,2,2) -> w2t[k = i*4+kh*2+kw][o]
__global__ void k_w2t(const float* __restrict__ srw, float* __restrict__ w2t){
  int t = blockIdx.x*256 + threadIdx.x;          // 262144 total
  int k = t >> 8, o = t & 255;
  w2t[t] = srw[o*1024 + k];                      // srw[o][i][kh][kw] = srw[o*1024 + k]
}

// ---- kernel 1: q projection.  q[b][n][c] = sum_i x[b][i][n] * Wq[i][c]
// grid (49, 4, 4) = (n-tile, c-tile, b); block (16,16); tx->c (coalesced stores), ty->n
__global__ void k_qproj(const float* __restrict__ x, const float* __restrict__ Wq,
                        float* __restrict__ qout){
  __shared__ float As[16][64];   // [kk][nn]
  __shared__ float Bs[16][64];   // [kk][cc]
  const int b  = blockIdx.z;
  const int n0 = blockIdx.x*64, c0 = blockIdx.y*64;
  const int tx = threadIdx.x, ty = threadIdx.y;
  const int t  = ty*16+tx, lr = t>>4, lc = (t&15)*4;
  float acc[4][4] = {};
  for (int k0=0; k0<CD; k0+=16){
    *(float4*)&As[lr][lc] = ld4(&x[((size_t)b*CD + k0+lr)*NTOK + n0+lc]);
    *(float4*)&Bs[lr][lc] = ld4(&Wq[(size_t)(k0+lr)*CD + c0+lc]);
    __syncthreads();
#pragma unroll
    for (int kk=0; kk<16; ++kk){
      float4 a4 = *(float4*)&As[kk][ty*4];
      float4 b4 = *(float4*)&Bs[kk][tx*4];
      float a[4]={a4.x,a4.y,a4.z,a4.w}, w[4]={b4.x,b4.y,b4.z,b4.w};
#pragma unroll
      for (int i=0;i<4;++i)
#pragma unroll
        for (int j=0;j<4;++j) acc[i][j] += a[i]*w[j];
    }
    __syncthreads();
  }
#pragma unroll
  for (int i=0;i<4;++i){
    float4 o4 = {acc[i][0],acc[i][1],acc[i][2],acc[i][3]};
    *(float4*)&qout[((size_t)b*NTOK + n0+ty*4+i)*CD + c0 + tx*4] = o4;
  }
}

// ---- kernel 2: conv as GEMM. out[m=b*784+nk][o] = sum_k in(m,k)*w2t[k][o] + srb[o]
// in(m, k=i*4+kh*2+kw) = x[b][i][2p+kh][2q+kw]; grid (49, 4); block (16,16)
__global__ void k_conv(const float* __restrict__ x, const float* __restrict__ w2t,
                       const float* __restrict__ srb, float* __restrict__ kvln){
  __shared__ float As[16][64];   // [kk][mm]
  __shared__ float Bs[16][64];   // [kk][oo]
  const int m0 = blockIdx.x*64, c0 = blockIdx.y*64;
  const int tx = threadIdx.x, ty = threadIdx.y;
  const int t  = ty*16+tx, lr = t>>4, lc = (t&15)*4;
  float acc[4][4] = {};
  for (int k0=0; k0<1024; k0+=16){
    int k = k0+lr, ci = k>>2, kh = (k>>1)&1, kw = k&1;
#pragma unroll
    for (int u=0; u<4; ++u){
      int m = m0+lc+u, bb = m/NKV, nk = m%NKV, pp = nk/28, qq = nk%28;
      As[lr][lc+u] = x[(((size_t)bb*CD + ci)*56 + 2*pp+kh)*56 + 2*qq+kw];
    }
    *(float4*)&Bs[lr][lc] = ld4(&w2t[(size_t)k*CD + c0+lc]);
    __syncthreads();
#pragma unroll
    for (int kk=0; kk<16; ++kk){
      float4 a4 = *(float4*)&As[kk][ty*4];
      float4 b4 = *(float4*)&Bs[kk][tx*4];
      float a[4]={a4.x,a4.y,a4.z,a4.w}, w[4]={b4.x,b4.y,b4.z,b4.w};
#pragma unroll
      for (int i=0;i<4;++i)
#pragma unroll
        for (int j=0;j<4;++j) acc[i][j] += a[i]*w[j];
    }
    __syncthreads();
  }
#pragma unroll
  for (int i=0;i<4;++i){
    int m = m0+ty*4+i, c = c0+tx*4;
    float4 o4 = {acc[i][0]+srb[c], acc[i][1]+srb[c+1], acc[i][2]+srb[c+2], acc[i][3]+srb[c+3]};
    *(float4*)&kvln[(size_t)m*CD + c] = o4;
  }
}

// ---- kernel 3: LayerNorm over C=256 per row, in-place on kvln. grid 3136, block 256
__global__ void k_ln(float* __restrict__ kvln, const float* __restrict__ g,
                     const float* __restrict__ bt){
  const int row = blockIdx.x, t = threadIdx.x;
  float v = kvln[(size_t)row*CD + t];
  float s = v, s2 = v*v;
#pragma unroll
  for (int o=32; o>0; o>>=1){ s += __shfl_down(s,o); s2 += __shfl_down(s2,o); }
  __shared__ float ps[4], ps2[4];
  int wid = t>>6, lane = t&63;
  if (lane==0){ ps[wid]=s; ps2[wid]=s2; }
  __syncthreads();
  if (t==0){
    float a = ps[0]+ps[1]+ps[2]+ps[3];
    float a2 = ps2[0]+ps2[1]+ps2[2]+ps2[3];
    float mu = a*(1.f/CD);
    float var = a2*(1.f/CD) - mu*mu;
    ps[0] = mu; ps2[0] = rsqrtf(var + 1e-5f);
  }
  __syncthreads();
  float mu = ps[0], rs = ps2[0];
  kvln[(size_t)row*CD + t] = (v-mu)*rs*g[t] + bt[t];
}

// ---- kernel 4: kv projection + scatter.  kv[m][c2] = sum_i kvln[m][i]*Wkv[i][c2]
// c2 = d*16 + h*2 + w  (head_dim slowest, w fastest).  grid (49, 8); block (16,16)
__global__ void k_kv(const float* __restrict__ kvln, const float* __restrict__ Wkv,
                     float* __restrict__ kb, float* __restrict__ vb){
  __shared__ float As[64][17];   // [mm][kk], padded
  __shared__ float Bs[16][64];   // [kk][cc]
  const int m0 = blockIdx.x*64, c0 = blockIdx.y*64;
  const int tx = threadIdx.x, ty = threadIdx.y, t = ty*16+tx;
  const int ar = t>>2, ac = (t&3)*4;
  const int lr = t>>4, lc = (t&15)*4;
  float acc[4][4] = {};
  for (int k0=0; k0<CD; k0+=16){
    float4 av = ld4(&kvln[(size_t)(m0+ar)*CD + k0+ac]);
    As[ar][ac]=av.x; As[ar][ac+1]=av.y; As[ar][ac+2]=av.z; As[ar][ac+3]=av.w;
    *(float4*)&Bs[lr][lc] = ld4(&Wkv[(size_t)(k0+lr)*512 + c0+lc]);
    __syncthreads();
#pragma unroll
    for (int kk=0; kk<16; ++kk){
      float a[4];
#pragma unroll
      for (int i=0;i<4;++i) a[i] = As[ty*4+i][kk];
      float4 b4 = *(float4*)&Bs[kk][tx*4];
      float w[4]={b4.x,b4.y,b4.z,b4.w};
#pragma unroll
      for (int i=0;i<4;++i)
#pragma unroll
        for (int j=0;j<4;++j) acc[i][j] += a[i]*w[j];
    }
    __syncthreads();
  }
#pragma unroll
  for (int i=0;i<4;++i){
    int m = m0+ty*4+i, bq = m/NKV, nk = m%NKV;
#pragma unroll
    for (int j=0;j<4;++j){
      int c2 = c0+tx*4+j, d = c2>>4, hh = (c2>>1)&7;
      float* dst = (c2&1) ? vb : kb;
      dst[(((size_t)bq*NH+hh)*NKV + nk)*HD + d] = acc[i][j];
    }
  }
}

// ---- kernel 5: fused attention (no-max online softmax), partials over 2 kv-splits.
// grid (7, 2, 32) = (n-chunk of 512 rows, kv-part, b*8+h); block 256; 2 rows/thread
__global__ __launch_bounds__(256) void k_attn(
    const float* __restrict__ q, const float* __restrict__ kb,
    const float* __restrict__ vb, const float* __restrict__ pos,
    float* __restrict__ pacc, float* __restrict__ pS){
  __shared__ float Kt[56*32];
  __shared__ float Vt[56*32];
  const int bh = blockIdx.z, part = blockIdx.y;
  const int t = threadIdx.x;
  const int n0 = blockIdx.x*512 + t*2;
  const int b = bh >> 3;
  const bool act = (n0 < NTOK);
  float qv[2][32];
  float acc[2][32] = {};
  float S[2] = {0.f, 0.f};
  int tb[2] = {0,0};
  if (act){
#pragma unroll
    for (int r=0;r<2;++r){
      int n = n0 + r;
      const float4* qp = (const float4*)&q[((size_t)b*NTOK + n)*CD + (bh&7)*HD];
#pragma unroll
      for (int d4=0; d4<8; ++d4){
        float4 v = qp[d4];
        qv[r][d4*4+0]=v.x; qv[r][d4*4+1]=v.y; qv[r][d4*4+2]=v.z; qv[r][d4*4+3]=v.w;
      }
      int nr = n/56, nc = n%56;
      tb[r] = (55-nr)*PEW + (55-nc);
    }
  }
  const size_t kvbase = (size_t)bh * (NKV*HD);
  for (int tt = part*7; tt < part*7+7; ++tt){
    __syncthreads();
#pragma unroll
    for (int j=0;j<7;++j){
      Kt[t + j*256] = kb[kvbase + (size_t)tt*1792 + t + j*256];
      Vt[t + j*256] = vb[kvbase + (size_t)tt*1792 + t + j*256];
    }
    __syncthreads();
    if (act){
      for (int mm=0; mm<56; ++mm){
        const float4* kp = (const float4*)&Kt[mm*32];
        float lg0=0.f, lg1=0.f;
#pragma unroll
        for (int d4=0; d4<8; ++d4){
          float4 k4 = kp[d4];
          lg0 += qv[0][d4*4+0]*k4.x + qv[0][d4*4+1]*k4.y + qv[0][d4*4+2]*k4.z + qv[0][d4*4+3]*k4.w;
          lg1 += qv[1][d4*4+0]*k4.x + qv[1][d4*4+1]*k4.y + qv[1][d4*4+2]*k4.z + qv[1][d4*4+3]*k4.w;
        }
        float bias0 = pos[tb[0] + tt*PEW + mm];
        float bias1 = pos[tb[1] + tt*PEW + mm];
        float p0 = __expf(lg0*SCALE + bias0);
        float p1 = __expf(lg1*SCALE + bias1);
        S[0] += p0; S[1] += p1;
        const float4* vp = (const float4*)&Vt[mm*32];
#pragma unroll
        for (int d4=0; d4<8; ++d4){
          float4 v4 = vp[d4];
          acc[0][d4*4+0] += p0*v4.x; acc[0][d4*4+1] += p0*v4.y;
          acc[0][d4*4+2] += p0*v4.z; acc[0][d4*4+3] += p0*v4.w;
          acc[1][d4*4+0] += p1*v4.x; acc[1][d4*4+1] += p1*v4.y;
          acc[1][d4*4+2] += p1*v4.z; acc[1][d4*4+3] += p1*v4.w;
        }
      }
    }
  }
  if (act){
#pragma unroll
    for (int r=0;r<2;++r){
      size_t row = (size_t)part*(32*NTOK) + (size_t)bh*NTOK + (n0+r);
      float4* op = (float4*)&pacc[row*HD];
#pragma unroll
      for (int d4=0; d4<8; ++d4){
        float4 o4 = {acc[r][d4*4+0], acc[r][d4*4+1], acc[r][d4*4+2], acc[r][d4*4+3]};
        op[d4] = o4;
      }
      pS[row] = S[r];
    }
  }
}

// ---- kernel 6: combine 2 kv-split partials -> attn_out (B, N, C). grid 392, block 256
__global__ void k_comb(const float* __restrict__ pacc, const float* __restrict__ pS,
                       float* __restrict__ aout){
  const int row = blockIdx.x*256 + threadIdx.x;   // < 100352
  const int bh = row / NTOK, n = row % NTOK;
  const int b = bh >> 3, h = bh & 7;
  float inv = 1.f / (pS[row] + pS[32*NTOK + row]);
  const float4* a0 = (const float4*)&pacc[(size_t)row*HD];
  const float4* a1 = (const float4*)&pacc[((size_t)32*NTOK + row)*HD];
  float4* o = (float4*)&aout[((size_t)b*NTOK + n)*CD + h*HD];
#pragma unroll
  for (int d4=0; d4<8; ++d4){
    float4 u = a0[d4], w = a1[d4];
    float4 r = {(u.x+w.x)*inv, (u.y+w.y)*inv, (u.z+w.z)*inv, (u.w+w.w)*inv};
    o[d4] = r;
  }
}

// ---- kernel 7: out projection + transpose to (B, C, H, W).
// out[b][c][n] = sum_i aout[b][n][i]*pw[i][c] + pb[c].  grid (196, 4); tx->n, ty->c
__global__ void k_proj(const float* __restrict__ ain, const float* __restrict__ pw,
                       const float* __restrict__ pb, float* __restrict__ out){
  __shared__ float As[64][17];   // [mm][kk]
  __shared__ float Bs[16][64];   // [kk][cc]
  const int m0 = blockIdx.x*64, c0 = blockIdx.y*64;
  const int tx = threadIdx.x, ty = threadIdx.y, t = ty*16+tx;
  const int ar = t>>2, ac = (t&3)*4;
  const int lr = t>>4, lc = (t&15)*4;
  float acc[4][4] = {};   // [cj][mi]
  for (int k0=0; k0<CD; k0+=16){
    float4 av = ld4(&ain[(size_t)(m0+ar)*CD + k0+ac]);
    As[ar][ac]=av.x; As[ar][ac+1]=av.y; As[ar][ac+2]=av.z; As[ar][ac+3]=av.w;
    *(float4*)&Bs[lr][lc] = ld4(&pw[(size_t)(k0+lr)*CD + c0+lc]);
    __syncthreads();
#pragma unroll
    for (int kk=0; kk<16; ++kk){
      float a[4];
#pragma unroll
      for (int i=0;i<4;++i) a[i] = As[tx*4+i][kk];
      float4 b4 = *(float4*)&Bs[kk][ty*4];
      float w[4]={b4.x,b4.y,b4.z,b4.w};
#pragma unroll
      for (int j=0;j<4;++j)
#pragma unroll
        for (int i=0;i<4;++i) acc[j][i] += w[j]*a[i];
    }
    __syncthreads();
  }
  const int m = m0 + tx*4;
  const int b = m / NTOK, n = m % NTOK;
#pragma unroll
  for (int j=0;j<4;++j){
    int c = c0 + ty*4 + j;
    float bias = pb[c];
    float4 o4 = {acc[j][0]+bias, acc[j][1]+bias, acc[j][2]+bias, acc[j][3]+bias};
    *(float4*)&out[((size_t)b*CD + c)*NTOK + n] = o4;
  }
}

extern "C" void kernel_launch(void* const* d_in, const int* in_sizes, int n_in,
                              void* d_out, int out_size, void* d_ws, size_t ws_size,
                              hipStream_t stream){
  const float* x   = (const float*)d_in[0];
  const float* Wq  = (const float*)d_in[1];
  const float* Wkv = (const float*)d_in[2];
  const float* srw = (const float*)d_in[3];
  const float* srb = (const float*)d_in[4];
  const float* lng = (const float*)d_in[5];
  const float* lnb = (const float*)d_in[6];
  const float* pos = (const float*)d_in[7];
  const float* pw  = (const float*)d_in[8];
  const float* pb  = (const float*)d_in[9];
  float* out = (float*)d_out;

  float* ws   = (float*)d_ws;
  float* w2t  = ws;                  // 262144
  float* qbuf = w2t  + 262144;       // 3211264  q (B,N,C)
  float* kvln = qbuf + 3211264;      // 802816   (B*Nk, C)
  float* kb   = kvln + 802816;       // 802816   (B,h,Nk,hd)
  float* vb   = kb   + 802816;       // 802816
  float* pacc = vb   + 802816;       // 6422528  2 parts x 100352 rows x 32
  float* pS   = pacc + 6422528;      // 200704
  float* aout = pS   + 200704;       // 3211264  attn out (B,N,C)

  k_w2t  <<<1024, 256, 0, stream>>>(srw, w2t);
  k_qproj<<<dim3(49,4,4), dim3(16,16), 0, stream>>>(x, Wq, qbuf);
  k_conv <<<dim3(49,4),   dim3(16,16), 0, stream>>>(x, w2t, srb, kvln);
  k_ln   <<<3136, 256, 0, stream>>>(kvln, lng, lnb);
  k_kv   <<<dim3(49,8),   dim3(16,16), 0, stream>>>(kvln, Wkv, kb, vb);
  k_attn <<<dim3(7,2,32), 256, 0, stream>>>(qbuf, kb, vb, pos, pacc, pS);
  k_comb <<<392, 256, 0, stream>>>(pacc, pS, aout);
  k_proj <<<dim3(196,4),  dim3(16,16), 0, stream>>>(aout, pw, pb, out);
}

// Round 2
// 227.784 us; speedup vs baseline: 2.3920x; 2.3920x over previous
//
#include <hip/hip_runtime.h>

typedef float f32x4 __attribute__((ext_vector_type(4)));
typedef short s16x8 __attribute__((ext_vector_type(8)));
typedef unsigned short u16x4 __attribute__((ext_vector_type(4)));

#define MFMA16(a,b,c) __builtin_amdgcn_mfma_f32_16x16x32_bf16(a,b,c,0,0,0)

#define NTOK 3136
#define NKV  784
#define NKVP 800     // padded keys
#define CD   256
#define NH   8
#define HD   32
#define PEW  111
#define SC2  (0.17677669529663687f * 1.4426950408889634f)  // scale * log2(e)

static __device__ __forceinline__ unsigned short f2b(float f){
  unsigned int u = __float_as_uint(f);
  return (unsigned short)((u + 0x7fffu + ((u>>16)&1u)) >> 16);
}
static __device__ __forceinline__ float b2f(unsigned short u){
  return __uint_as_float(((unsigned int)u)<<16);
}

// ---- prep: transpose weights to [n][k] bf16; srw copied straight (already o-major)
__global__ void k_prepw(const float* __restrict__ Wq, const float* __restrict__ Wkv,
                        const float* __restrict__ pw, const float* __restrict__ srw,
                        unsigned short* __restrict__ WqT, unsigned short* __restrict__ WkvT,
                        unsigned short* __restrict__ pwT, unsigned short* __restrict__ srwb){
  int i = blockIdx.x*256 + threadIdx.x;             // 524288 total
  if (i < 65536){ int nn=i>>8, kk=i&255; WqT[i] = f2b(Wq[kk*256+nn]); }
  else if (i < 196608){ int j=i-65536; int c2=j>>8, kk=j&255; WkvT[j] = f2b(Wkv[kk*512+c2]); }
  else if (i < 262144){ int j=i-196608; int cc=j>>8, kk=j&255; pwT[j] = f2b(pw[kk*256+cc]); }
  else { int j=i-262144; srwb[j] = f2b(srw[j]); }
}

// ---- bias2[n][key] = pos[rel]*log2e (bf16), pad keys -> -30000
__global__ void k_bias(const float* __restrict__ pos, unsigned short* __restrict__ bias2){
  int key = blockIdx.x*256 + threadIdx.x;
  int n = blockIdx.y;
  if (key >= NKVP) return;
  float v;
  if (key < NKV){
    int nr = (n*9363)>>19, nc = n - nr*56;
    int tt = (key*9363)>>19, mm = key - tt*56;
    v = pos[(tt-nr+55)*PEW + (mm-nc+55)] * 1.4426950408889634f;
  } else v = -30000.f;
  bias2[(size_t)n*NKVP + key] = f2b(v);
}

// ---- zero K/V pad rows (keys 784..799)
__global__ void k_pad(unsigned short* __restrict__ kb, unsigned short* __restrict__ vT){
  int i = blockIdx.x*256 + threadIdx.x;             // 32768
  if (i < 16384){
    int bh=i>>9, r=i&511, key=784+(r>>5), d=r&31;
    kb[((size_t)bh*NKVP + key)*HD + d] = 0;
  } else {
    int j=i-16384;
    int bh=j>>9, r=j&511, d=r>>4, key=784+(r&15);
    vT[((size_t)bh*HD + d)*NKVP + key] = 0;
  }
}

// ---- q projection: q[b][n][c] = x(b,:,n) . Wq(:,c); MFMA, no LDS. grid (196,4)
__global__ __launch_bounds__(256) void k_qproj(const float* __restrict__ x,
      const unsigned short* __restrict__ WqT, unsigned short* __restrict__ qb){
  const int tid=threadIdx.x, wv=tid>>6, l=tid&63, g=l>>4, ln16=l&15;
  const int bI = blockIdx.x/49;
  const int n0 = (blockIdx.x%49)*64;
  const int m0 = n0 + (wv>>1)*32;
  const int c0 = blockIdx.y*64 + (wv&1)*32;
  const float* xb = x + (size_t)bI*CD*NTOK;
  f32x4 acc[2][2] = {};
  for (int k0=0; k0<CD; k0+=32){
    s16x8 a[2], bf[2];
#pragma unroll
    for (int mi=0; mi<2; ++mi){
      int n = m0 + mi*16 + ln16;
      const float* xp = xb + (size_t)(k0+g*8)*NTOK + n;
#pragma unroll
      for (int j=0;j<8;++j) a[mi][j] = (short)f2b(xp[(size_t)j*NTOK]);
    }
#pragma unroll
    for (int ni=0; ni<2; ++ni)
      bf[ni] = *(const s16x8*)&WqT[(size_t)(c0+ni*16+ln16)*CD + k0 + g*8];
#pragma unroll
    for (int mi=0;mi<2;++mi)
#pragma unroll
      for (int ni=0;ni<2;++ni) acc[mi][ni] = MFMA16(a[mi], bf[ni], acc[mi][ni]);
  }
#pragma unroll
  for (int mi=0;mi<2;++mi)
#pragma unroll
    for (int ni=0;ni<2;++ni){
      int c = c0 + ni*16 + ln16;
#pragma unroll
      for (int r=0;r<4;++r){
        int n = m0 + mi*16 + g*4 + r;
        qb[((size_t)bI*NTOK + n)*CD + c] = f2b(acc[mi][ni][r]);
      }
    }
}

// ---- conv as GEMM (im2col on the fly): convo[m][o] = sum_k x(m,k)*srw[o][k] + srb. grid (49,4)
__global__ __launch_bounds__(256) void k_conv(const float* __restrict__ x,
      const unsigned short* __restrict__ srwb, const float* __restrict__ srb,
      float* __restrict__ convo){
  const int tid=threadIdx.x, wv=tid>>6, l=tid&63, g=l>>4, ln16=l&15;
  const int m0 = blockIdx.x*64 + (wv>>1)*32;
  const int c0 = blockIdx.y*64 + (wv&1)*32;
  size_t abase[2];
#pragma unroll
  for (int mi=0;mi<2;++mi){
    int m = m0 + mi*16 + ln16;
    int bb = (m>=2352)?3:(m>=1568)?2:(m>=784)?1:0;
    int nk = m - bb*784;
    int pp = (nk*9363)>>18, qq = nk - pp*28;
    abase[mi] = (size_t)bb*CD*NTOK + (size_t)(2*pp)*56 + 2*qq;
  }
  const int off[8] = {0,1,56,57,3136,3137,3192,3193};
  f32x4 acc[2][2] = {};
  for (int k0=0; k0<1024; k0+=32){
    int cib = (k0>>2) + g*2;
    s16x8 a[2], bf[2];
#pragma unroll
    for (int mi=0;mi<2;++mi){
      const float* xp = x + abase[mi] + (size_t)cib*NTOK;
#pragma unroll
      for (int j=0;j<8;++j) a[mi][j] = (short)f2b(xp[off[j]]);
    }
#pragma unroll
    for (int ni=0;ni<2;++ni)
      bf[ni] = *(const s16x8*)&srwb[(size_t)(c0+ni*16+ln16)*1024 + k0 + g*8];
#pragma unroll
    for (int mi=0;mi<2;++mi)
#pragma unroll
      for (int ni=0;ni<2;++ni) acc[mi][ni] = MFMA16(a[mi], bf[ni], acc[mi][ni]);
  }
#pragma unroll
  for (int mi=0;mi<2;++mi)
#pragma unroll
    for (int ni=0;ni<2;++ni){
      int c = c0 + ni*16 + ln16;
      float bias = srb[c];
#pragma unroll
      for (int r=0;r<4;++r){
        int m = m0 + mi*16 + g*4 + r;
        convo[(size_t)m*CD + c] = acc[mi][ni][r] + bias;
      }
    }
}

// ---- LayerNorm (f32 in, bf16 out). grid 3136, block 256
__global__ void k_ln(const float* __restrict__ co, const float* __restrict__ gam,
                     const float* __restrict__ bet, unsigned short* __restrict__ kvbf){
  const int row = blockIdx.x, t = threadIdx.x;
  float v = co[(size_t)row*CD + t];
  float s = v, s2 = v*v;
#pragma unroll
  for (int o=32; o>0; o>>=1){ s += __shfl_down(s,o); s2 += __shfl_down(s2,o); }
  __shared__ float ps[4], ps2[4];
  int wid = t>>6, lane = t&63;
  if (lane==0){ ps[wid]=s; ps2[wid]=s2; }
  __syncthreads();
  if (t==0){
    float a = ps[0]+ps[1]+ps[2]+ps[3];
    float a2 = ps2[0]+ps2[1]+ps2[2]+ps2[3];
    float mu = a*(1.f/CD);
    float var = a2*(1.f/CD) - mu*mu;
    ps[0] = mu; ps2[0] = rsqrtf(var + 1e-5f);
  }
  __syncthreads();
  float mu = ps[0], rs = ps2[0];
  kvbf[(size_t)row*CD + t] = f2b((v-mu)*rs*gam[t] + bet[t]);
}

// ---- kv projection + scatter to k (bh,key,hd) and vT (bh,hd,key), bf16. grid (49,8)
__global__ __launch_bounds__(256) void k_kv(const unsigned short* __restrict__ kvbf,
      const unsigned short* __restrict__ WkvT, unsigned short* __restrict__ kb,
      unsigned short* __restrict__ vT){
  const int tid=threadIdx.x, wv=tid>>6, l=tid&63, g=l>>4, ln16=l&15;
  const int m0 = blockIdx.x*64 + (wv>>1)*32;
  const int c0 = blockIdx.y*64 + (wv&1)*32;
  f32x4 acc[2][2] = {};
  for (int k0=0; k0<CD; k0+=32){
    s16x8 a[2], bf[2];
#pragma unroll
    for (int mi=0;mi<2;++mi)
      a[mi] = *(const s16x8*)&kvbf[(size_t)(m0+mi*16+ln16)*CD + k0 + g*8];
#pragma unroll
    for (int ni=0;ni<2;++ni)
      bf[ni] = *(const s16x8*)&WkvT[(size_t)(c0+ni*16+ln16)*CD + k0 + g*8];
#pragma unroll
    for (int mi=0;mi<2;++mi)
#pragma unroll
      for (int ni=0;ni<2;++ni) acc[mi][ni] = MFMA16(a[mi], bf[ni], acc[mi][ni]);
  }
#pragma unroll
  for (int mi=0;mi<2;++mi)
#pragma unroll
    for (int ni=0;ni<2;++ni){
      int c2 = c0 + ni*16 + ln16;
      int d = c2>>4, hh = (c2>>1)&7;
#pragma unroll
      for (int r=0;r<4;++r){
        int m = m0 + mi*16 + g*4 + r;
        int bq = (m>=2352)?3:(m>=1568)?2:(m>=784)?1:0;
        int nk = m - bq*784;
        unsigned short val = f2b(acc[mi][ni][r]);
        if (c2&1) vT[(((size_t)bq*NH+hh)*HD + d)*NKVP + nk] = val;
        else      kb[(((size_t)bq*NH+hh)*NKVP + nk)*HD + d] = val;
      }
    }
}

// ---- fused MFMA attention. grid (49, 32) = (n-tile/64, b*8+h); 4 waves x 16 q-rows
__global__ __launch_bounds__(256) void k_attn(const unsigned short* __restrict__ qb,
      const unsigned short* __restrict__ kb, const unsigned short* __restrict__ vT,
      const unsigned short* __restrict__ bias2, unsigned short* __restrict__ aout){
  __shared__ unsigned short Pl[4][16][40];   // per-wave P tile, padded stride
  const int tid=threadIdx.x, wv=tid>>6, l=tid&63, g=l>>4, ln16=l&15;
  const int bh = blockIdx.y, b = bh>>3, h = bh&7;
  const int nw = blockIdx.x*64 + wv*16;       // wave's first q-row
  const s16x8 qf = *(const s16x8*)&qb[((size_t)b*NTOK + nw + ln16)*CD + h*HD + g*8];
  const unsigned short* kbp = kb + (size_t)bh*NKVP*HD;
  const unsigned short* vbp = vT + (size_t)bh*HD*NKVP;
  const unsigned short* bp  = bias2 + (size_t)(nw + ln16)*NKVP;
  f32x4 accO0 = {}, accO1 = {};
  float S = 0.f;
  const f32x4 zf = {};
  for (int ks=0; ks<NKVP; ks+=32){
    s16x8 ka0 = *(const s16x8*)&kbp[(size_t)(ks+ln16)*HD + g*8];
    s16x8 ka1 = *(const s16x8*)&kbp[(size_t)(ks+16+ln16)*HD + g*8];
    f32x4 d0 = MFMA16(ka0, qf, zf);
    f32x4 d1 = MFMA16(ka1, qf, zf);
    u16x4 bb0 = *(const u16x4*)&bp[ks + g*4];
    u16x4 bb1 = *(const u16x4*)&bp[ks + 16 + g*4];
    float p[8];
#pragma unroll
    for (int r=0;r<4;++r){
      p[r]   = exp2f(d0[r]*SC2 + b2f(bb0[r]));
      p[4+r] = exp2f(d1[r]*SC2 + b2f(bb1[r]));
    }
    S += ((p[0]+p[1])+(p[2]+p[3])) + ((p[4]+p[5])+(p[6]+p[7]));
    unsigned int w0 = (unsigned int)f2b(p[0]) | ((unsigned int)f2b(p[1])<<16);
    unsigned int w1 = (unsigned int)f2b(p[2]) | ((unsigned int)f2b(p[3])<<16);
    unsigned int w2 = (unsigned int)f2b(p[4]) | ((unsigned int)f2b(p[5])<<16);
    unsigned int w3 = (unsigned int)f2b(p[6]) | ((unsigned int)f2b(p[7])<<16);
    *(uint2*)&Pl[wv][ln16][g*4]      = make_uint2(w0, w1);
    *(uint2*)&Pl[wv][ln16][16+g*4]   = make_uint2(w2, w3);
    s16x8 pf = *(const s16x8*)&Pl[wv][ln16][g*8];
    s16x8 v0 = *(const s16x8*)&vbp[(size_t)ln16*NKVP + ks + g*8];
    s16x8 v1 = *(const s16x8*)&vbp[(size_t)(16+ln16)*NKVP + ks + g*8];
    accO0 = MFMA16(pf, v0, accO0);
    accO1 = MFMA16(pf, v1, accO1);
  }
  S += __shfl_xor(S, 16);
  S += __shfl_xor(S, 32);
#pragma unroll
  for (int r=0;r<4;++r){
    float Sr = __shfl(S, g*4 + r);
    float inv = 1.f / Sr;
    int n = nw + g*4 + r;
    aout[((size_t)b*NTOK + n)*CD + h*HD + ln16]      = f2b(accO0[r]*inv);
    aout[((size_t)b*NTOK + n)*CD + h*HD + 16 + ln16] = f2b(accO1[r]*inv);
  }
}

// ---- out projection + transpose store to (B,C,H,W). grid (196,4)
__global__ __launch_bounds__(256) void k_proj(const unsigned short* __restrict__ ain,
      const unsigned short* __restrict__ pwT, const float* __restrict__ pb,
      float* __restrict__ out){
  const int tid=threadIdx.x, wv=tid>>6, l=tid&63, g=l>>4, ln16=l&15;
  const int bI = blockIdx.x/49;
  const int n0 = (blockIdx.x%49)*64;
  const int m0 = n0 + (wv>>1)*32;
  const int c0 = blockIdx.y*64 + (wv&1)*32;
  f32x4 acc[2][2] = {};
  for (int k0=0; k0<CD; k0+=32){
    s16x8 a[2], bf[2];
#pragma unroll
    for (int mi=0;mi<2;++mi)
      a[mi] = *(const s16x8*)&ain[((size_t)bI*NTOK + m0+mi*16+ln16)*CD + k0 + g*8];
#pragma unroll
    for (int ni=0;ni<2;++ni)
      bf[ni] = *(const s16x8*)&pwT[(size_t)(c0+ni*16+ln16)*CD + k0 + g*8];
#pragma unroll
    for (int mi=0;mi<2;++mi)
#pragma unroll
      for (int ni=0;ni<2;++ni) acc[mi][ni] = MFMA16(a[mi], bf[ni], acc[mi][ni]);
  }
#pragma unroll
  for (int ni=0;ni<2;++ni){
    int c = c0 + ni*16 + ln16;
    float bias = pb[c];
#pragma unroll
    for (int mi=0;mi<2;++mi){
      int n = m0 + mi*16 + g*4;
      f32x4 o = acc[mi][ni];
      o[0]+=bias; o[1]+=bias; o[2]+=bias; o[3]+=bias;
      *(f32x4*)&out[((size_t)bI*CD + c)*NTOK + n] = o;
    }
  }
}

extern "C" void kernel_launch(void* const* d_in, const int* in_sizes, int n_in,
                              void* d_out, int out_size, void* d_ws, size_t ws_size,
                              hipStream_t stream){
  const float* x   = (const float*)d_in[0];
  const float* Wq  = (const float*)d_in[1];
  const float* Wkv = (const float*)d_in[2];
  const float* srw = (const float*)d_in[3];
  const float* srb = (const float*)d_in[4];
  const float* lng = (const float*)d_in[5];
  const float* lnb = (const float*)d_in[6];
  const float* pos = (const float*)d_in[7];
  const float* pw  = (const float*)d_in[8];
  const float* pb  = (const float*)d_in[9];
  float* out = (float*)d_out;

  unsigned char* p = (unsigned char*)d_ws;
  unsigned short* WqT  = (unsigned short*)(p + 0);
  unsigned short* WkvT = (unsigned short*)(p + 131072);
  unsigned short* pwT  = (unsigned short*)(p + 393216);
  unsigned short* srwb = (unsigned short*)(p + 524288);
  unsigned short* bias2= (unsigned short*)(p + 1048576);
  unsigned short* qbuf = (unsigned short*)(p + 6066176);
  float*          convo= (float*)        (p + 12488704);
  unsigned short* kvbf = (unsigned short*)(p + 15699968);
  unsigned short* kbuf = (unsigned short*)(p + 17305600);
  unsigned short* vT   = (unsigned short*)(p + 18944000);
  unsigned short* aout = (unsigned short*)(p + 20582400);

  k_prepw<<<2048, 256, 0, stream>>>(Wq, Wkv, pw, srw, WqT, WkvT, pwT, srwb);
  k_bias <<<dim3(4,3136), 256, 0, stream>>>(pos, bias2);
  k_pad  <<<128, 256, 0, stream>>>(kbuf, vT);
  k_qproj<<<dim3(196,4), 256, 0, stream>>>(x, WqT, qbuf);
  k_conv <<<dim3(49,4),  256, 0, stream>>>(x, srwb, srb, convo);
  k_ln   <<<3136, 256, 0, stream>>>(convo, lng, lnb, kvbf);
  k_kv   <<<dim3(49,8),  256, 0, stream>>>(kvbf, WkvT, kbuf, vT);
  k_attn <<<dim3(49,32), 256, 0, stream>>>(qbuf, kbuf, vT, bias2, aout);
  k_proj <<<dim3(196,4), 256, 0, stream>>>(aout, pwT, pb, out);
}